// Round 5
// baseline (805.361 us; speedup 1.0000x reference)
//
#include <hip/hip_runtime.h>
#include <math.h>

#define NN 10000
#define NE 160000
#define NB 8
#define TT 12
#define HP 64
#define HV 32

#define NBLK 1536                      // 6 blocks/CU * 256 CUs -> all co-resident (launch_bounds enforced)
#define NTHR 256
#define GRID_T (NBLK * NTHR)           // 393216
#define EB (NE * NB)                   // 1280000
#define NITER 4                        // ceil(EB / GRID_T)

typedef float v2 __attribute__((ext_vector_type(2)));

__device__ __forceinline__ v2 fma2(v2 a, v2 b, v2 c) { return __builtin_elementwise_fma(a, b, c); }

__device__ __forceinline__ void load_row12v(const float* __restrict__ p, v2* r2) {
  const float4* p4 = reinterpret_cast<const float4*>(p);
  float4 a = p4[0], b = p4[1], c = p4[2];
  r2[0] = (v2){a.x, a.y}; r2[1] = (v2){a.z, a.w};
  r2[2] = (v2){b.x, b.y}; r2[3] = (v2){b.z, b.w};
  r2[4] = (v2){c.x, c.y}; r2[5] = (v2){c.z, c.w};
}

__device__ __forceinline__ void load_row12(const float* __restrict__ p, float* row) {
  const float4* p4 = reinterpret_cast<const float4*>(p);
  float4 r0 = p4[0], r1 = p4[1], r2 = p4[2];
  row[0]=r0.x; row[1]=r0.y; row[2]=r0.z; row[3]=r0.w;
  row[4]=r1.x; row[5]=r1.y; row[6]=r1.z; row[7]=r1.w;
  row[8]=r2.x; row[9]=r2.y; row[10]=r2.z; row[11]=r2.w;
}

// ---- grid barrier: all NBLK blocks are resident (launch_bounds(256,6) guarantees 6 blocks/CU) ----
__device__ __forceinline__ void gridbar(unsigned* bar) {
  __syncthreads();
  if (threadIdx.x == 0) {
    __threadfence();  // release: write back dirty L2 (cross-XCD visibility)
    unsigned prev = __hip_atomic_fetch_add(bar, 1u, __ATOMIC_ACQ_REL, __HIP_MEMORY_SCOPE_AGENT);
    if (prev + 1u < (unsigned)NBLK) {
      while (__hip_atomic_load(bar, __ATOMIC_ACQUIRE, __HIP_MEMORY_SCOPE_AGENT) < (unsigned)NBLK)
        __builtin_amdgcn_s_sleep(8);
    }
    __threadfence();  // acquire: invalidate caches before reading others' data
  }
  __syncthreads();
}

// ---- zero the two barrier words each call (ws is re-poisoned 0xAA before every timed launch) ----
__global__ void k_init(unsigned* __restrict__ bars) {
  if (threadIdx.x < 2)
    __hip_atomic_store(&bars[threadIdx.x], 0u, __ATOMIC_RELEASE, __HIP_MEMORY_SCOPE_AGENT);
}

// ---- one NAM branch (packed-fp32): sigmoid(w2 . relu(LN(row@w^T + b))) ----
__device__ __forceinline__ float nam_branch(const v2* row2, const float* __restrict__ w,
                                            const float* __restrict__ bias,
                                            const float* __restrict__ g,
                                            const float* __restrict__ bb,
                                            const float* __restrict__ w2, float b2) {
  const v2* wv    = reinterpret_cast<const v2*>(w);     // [32][6]
  const v2* biasv = reinterpret_cast<const v2*>(bias);
  const v2* gv    = reinterpret_cast<const v2*>(g);
  const v2* bbv   = reinterpret_cast<const v2*>(bb);
  const v2* w2v   = reinterpret_cast<const v2*>(w2);
  v2 hp[HV / 2];
  v2 sp1 = {0.f,0.f}, sp2 = {0.f,0.f};
#pragma unroll
  for (int j2 = 0; j2 < HV / 2; ++j2) {
    v2 a0 = {0.f,0.f}, a1 = {0.f,0.f};
#pragma unroll
    for (int k2 = 0; k2 < 6; ++k2) {
      a0 = fma2(row2[k2], wv[(2 * j2) * 6 + k2], a0);
      a1 = fma2(row2[k2], wv[(2 * j2 + 1) * 6 + k2], a1);
    }
    v2 bp = biasv[j2];
    v2 h = {a0.x + a0.y + bp.x, a1.x + a1.y + bp.y};
    hp[j2] = h;
    sp1 += h;
    sp2 = fma2(h, h, sp2);
  }
  float s1 = sp1.x + sp1.y, s2 = sp2.x + sp2.y;
  float m = s1 * (1.f / HV);
  float var = s2 * (1.f / HV) - m * m;
  float inv = rsqrtf(var + 1e-5f);
  v2 inv2 = {inv, inv};
  float nmi = -m * inv;
  v2 nmi2 = {nmi, nmi};
  v2 acc2 = {0.f,0.f};
  v2 zero = {0.f,0.f};
#pragma unroll
  for (int j2 = 0; j2 < HV / 2; ++j2) {
    v2 tt = fma2(hp[j2], inv2, nmi2);
    v2 y = fma2(tt, gv[j2], bbv[j2]);
    y = __builtin_elementwise_max(y, zero);
    acc2 = fma2(y, w2v[j2], acc2);
  }
  float acc = acc2.x + acc2.y + b2;
  return 1.f / (1.f + __expf(-acc));
}

// ---- fused: phase0 (consts + nodeAgg + zero den/pred) | bar | phase1 (edges) | bar | phase2 (scatter) ----
__global__ __launch_bounds__(NTHR, 6) void k_main(
    const float* __restrict__ feature, const float* __restrict__ upstream,
    const float* __restrict__ downstream, const float* __restrict__ distance,
    const float* __restrict__ alpha, const int* __restrict__ src, const int* __restrict__ dst,
    const float* __restrict__ fc_w, const float* __restrict__ ln2_g, const float* __restrict__ ln2_b,
    const float* __restrict__ attn_w,
    const float* __restrict__ l11_w, const float* __restrict__ l11_b,
    const float* __restrict__ ln11_g, const float* __restrict__ ln11_b,
    const float* __restrict__ l12_w, const float* __restrict__ l12_b,
    const float* __restrict__ l21_w, const float* __restrict__ l21_b,
    const float* __restrict__ ln21_g, const float* __restrict__ ln21_b,
    const float* __restrict__ l22_w, const float* __restrict__ l22_b,
    const float* __restrict__ l3_w, const float* __restrict__ l3_b,
    float4* __restrict__ nodeAgg, float* __restrict__ den, float* __restrict__ consts,
    float* __restrict__ prodArr, unsigned* __restrict__ bars, float* __restrict__ pred) {
  int t0 = blockIdx.x * NTHR + threadIdx.x;

  // ---------- phase 0 ----------
  if (blockIdx.x == 0) {
    __shared__ float r1[NTHR], r2[NTHR];
    int c = threadIdx.x;
    float vg = 0.f, vb = 0.f;
    if (c < 2 * HP + 1) {
      float aw = attn_w[c];
      vg = aw * ln2_g[c];
      vb = aw * ln2_b[c];
    }
    r1[c] = vg; r2[c] = vb;
    __syncthreads();
    for (int off = 128; off > 0; off >>= 1) {
      if (c < off) { r1[c] += r1[c + off]; r2[c] += r2[c + off]; }
      __syncthreads();
    }
    if (c == 0) {
      consts[0] = r1[0];                           // S_wg
      consts[1] = r2[0];                           // S_wb
      consts[2] = attn_w[2 * HP] * ln2_g[2 * HP];  // wg for the T column
    }
  }

  if (t0 < NN * NB) {
    den[t0] = 0.f;
    pred[t0] = 0.f;
    v2 row2[6];
    load_row12v(feature + (size_t)t0 * TT, row2);
    const v2* wv  = reinterpret_cast<const v2*>(fc_w);   // [64][6]
    const v2* awv = reinterpret_cast<const v2*>(attn_w);
    const v2* gv  = reinterpret_cast<const v2*>(ln2_g);
    v2 A1p = {0.f,0.f}, A2p = {0.f,0.f}, Dsp = {0.f,0.f}, Ddp = {0.f,0.f};
#pragma unroll
    for (int c2 = 0; c2 < HP / 2; ++c2) {
      v2 a0 = {0.f,0.f}, a1 = {0.f,0.f};
#pragma unroll
      for (int k2 = 0; k2 < 6; ++k2) {
        a0 = fma2(row2[k2], wv[(2 * c2) * 6 + k2], a0);
        a1 = fma2(row2[k2], wv[(2 * c2 + 1) * 6 + k2], a1);
      }
      v2 zp = {a0.x + a0.y, a1.x + a1.y};
      A1p += zp;
      A2p = fma2(zp, zp, A2p);
      v2 wgs = awv[c2] * gv[c2];
      v2 wgd = awv[HP / 2 + c2] * gv[HP / 2 + c2];
      Dsp = fma2(wgs, zp, Dsp);
      Ddp = fma2(wgd, zp, Ddp);
    }
    float4 o;
    o.x = A1p.x + A1p.y; o.y = A2p.x + A2p.y; o.z = Dsp.x + Dsp.y; o.w = Ddp.x + Ddp.y;
    nodeAgg[t0] = o;
  }

  gridbar(bars + 0);

  // ---------- phase 1: per-(edge,batch) velocity, diffusion, attention ----------
  // consts were written by another block: agent-scope atomic loads (vector path, not stale K$)
  float c0 = __hip_atomic_load(&consts[0], __ATOMIC_RELAXED, __HIP_MEMORY_SCOPE_AGENT);
  float c1 = __hip_atomic_load(&consts[1], __ATOMIC_RELAXED, __HIP_MEMORY_SCOPE_AGENT);
  float c2 = __hip_atomic_load(&consts[2], __ATOMIC_RELAXED, __HIP_MEMORY_SCOPE_AGENT);

#pragma unroll 1
  for (int it = 0; it < NITER; ++it) {
    int q = t0 + it * GRID_T;
    if (q < EB) {
      int e = q >> 3, b = q & 7;
      int se = src[e], de = dst[e];

      v2 row2[6];
      load_row12v(upstream + (size_t)q * TT, row2);
      float xu = nam_branch(row2, l11_w, l11_b, ln11_g, ln11_b, l12_w, l12_b[0]);
      load_row12v(downstream + (size_t)q * TT, row2);
      float xd = nam_branch(row2, l21_w, l21_b, ln21_g, ln21_b, l22_w, l22_b[0]);

      float al = alpha[e];
      float vp = fmaf(l3_w[0], xu, fmaf(l3_w[1], xd, fmaf(l3_w[2], al, l3_b[0])));
      float v = fmaxf(vp, 0.f) + log1pf(__expf(-fabsf(vp)));  // stable softplus
      v = fminf(v, 3.f);
      float Tt = distance[e] / (v + 1e-5f);                   // IEEE div: rounding cliff below
      float Ti = fminf(fmaxf(rintf(Tt * 0.1f), 0.f), (float)(TT - 1));
      int n = TT - (int)Ti;  // 1..12
      float acl = fminf(fmaxf(al, 0.f), 1.f);
      float F = 1.f / (1.f + acl * Tt);
      float omF = 1.f - F;

      float row[TT];
      load_row12(feature + ((size_t)se * NB + b) * TT, row);
      float pw = 1.f, s = 0.f;
#pragma unroll
      for (int k = TT - 1; k >= 0; --k) {
        if (k <= n - 1) { s = fmaf(pw, row[k], s); pw *= omF; }
      }
      s *= F;

      float4 As = nodeAgg[(size_t)se * NB + b];
      float4 Ad = nodeAgg[(size_t)de * NB + b];
      float s1 = As.x + Ad.x + Tt;
      float s2 = As.y + Ad.y + Tt * Tt;
      float sd = As.z + Ad.w + c2 * Tt;

      float m = s1 * (1.f / 129.f);
      float var = s2 * (1.f / 129.f) - m * m;
      float inv = rsqrtf(var + 1e-5f);
      float a = fmaf(inv, sd - m * c0, c1);
      a = (a >= 0.f) ? a : 0.01f * a;  // leaky_relu 0.01

      float ex = __expf(a);            // |a| bounded (Cauchy-Schwarz on normalized zc): no overflow
      prodArr[q] = ex * s;
      atomicAdd(&den[(size_t)se * NB + b], ex);
    }
  }

  gridbar(bars + 1);

  // ---------- phase 2: pred[dst] += prod / den[src] ----------
#pragma unroll 1
  for (int it = 0; it < NITER; ++it) {
    int q = t0 + it * GRID_T;
    if (q < EB) {
      int e = q >> 3, b = q & 7;
      float p = prodArr[q] / den[(size_t)src[e] * NB + b];
      atomicAdd(&pred[(size_t)dst[e] * NB + b], p);
    }
  }
}

extern "C" void kernel_launch(void* const* d_in, const int* in_sizes, int n_in,
                              void* d_out, int out_size, void* d_ws, size_t ws_size,
                              hipStream_t stream) {
  const float* feature   = (const float*)d_in[0];
  const float* upstream  = (const float*)d_in[1];
  const float* downstream= (const float*)d_in[2];
  const float* distance  = (const float*)d_in[3];
  const int*   src       = (const int*)d_in[4];
  const int*   dst       = (const int*)d_in[5];
  const float* alpha     = (const float*)d_in[6];
  const float* fc_w      = (const float*)d_in[7];
  const float* ln2_g     = (const float*)d_in[8];
  const float* ln2_b     = (const float*)d_in[9];
  const float* attn_w    = (const float*)d_in[10];
  const float* l11_w     = (const float*)d_in[11];
  const float* l11_b     = (const float*)d_in[12];
  const float* ln11_g    = (const float*)d_in[13];
  const float* ln11_b    = (const float*)d_in[14];
  const float* l12_w     = (const float*)d_in[15];
  const float* l12_b     = (const float*)d_in[16];
  const float* l21_w     = (const float*)d_in[17];
  const float* l21_b     = (const float*)d_in[18];
  const float* ln21_g    = (const float*)d_in[19];
  const float* ln21_b    = (const float*)d_in[20];
  const float* l22_w     = (const float*)d_in[21];
  const float* l22_b     = (const float*)d_in[22];
  const float* l3_w      = (const float*)d_in[23];
  const float* l3_b      = (const float*)d_in[24];
  float* pred = (float*)d_out;

  // ws layout (floats): nodeAgg[320000] | den[80000] | consts[4] | prodArr[EB] | bars[2]
  float* ws = (float*)d_ws;
  float4* nodeAgg = (float4*)ws;
  float* den     = ws + (size_t)NN * NB * 4;
  float* consts  = den + (size_t)NN * NB;
  float* prodArr = consts + 4;
  unsigned* bars = (unsigned*)(prodArr + (size_t)EB);

  k_init<<<1, 64, 0, stream>>>(bars);
  k_main<<<NBLK, NTHR, 0, stream>>>(feature, upstream, downstream, distance, alpha, src, dst,
                                    fc_w, ln2_g, ln2_b, attn_w,
                                    l11_w, l11_b, ln11_g, ln11_b, l12_w, l12_b,
                                    l21_w, l21_b, ln21_g, ln21_b, l22_w, l22_b,
                                    l3_w, l3_b,
                                    nodeAgg, den, consts, prodArr, bars, pred);
}

// Round 7
// 233.068 us; speedup vs baseline: 3.4555x; 3.4555x over previous
//
#include <hip/hip_runtime.h>
#include <math.h>

#define NN 10000
#define NE 160000
#define NB 8
#define TT 12
#define HP 64
#define HV 32

typedef float v2 __attribute__((ext_vector_type(2)));

__device__ __forceinline__ v2 fma2(v2 a, v2 b, v2 c) { return __builtin_elementwise_fma(a, b, c); }

__device__ __forceinline__ void load_row12v(const float* __restrict__ p, v2* r2) {
  const float4* p4 = reinterpret_cast<const float4*>(p);
  float4 a = p4[0], b = p4[1], c = p4[2];
  r2[0] = (v2){a.x, a.y}; r2[1] = (v2){a.z, a.w};
  r2[2] = (v2){b.x, b.y}; r2[3] = (v2){b.z, b.w};
  r2[4] = (v2){c.x, c.y}; r2[5] = (v2){c.z, c.w};
}

// ---------------- zero ONLY the accumulated buffers (den, pred) ----------------
__global__ __launch_bounds__(256) void k_init(float4* __restrict__ den4, float4* __restrict__ pred4) {
  int i = blockIdx.x * 256 + threadIdx.x;
  float4 z; z.x = 0.f; z.y = 0.f; z.z = 0.f; z.w = 0.f;
  if (i < NN * NB / 4) { den4[i] = z; pred4[i] = z; }
}

// ---------------- per-(node,batch) attention aggregates {A1,A2,Dsrc,Ddst}; block 0 writes consts ----------------
__global__ __launch_bounds__(256) void k_node(const float* __restrict__ feature,
                                              const float* __restrict__ fc_w,
                                              const float* __restrict__ attn_w,
                                              const float* __restrict__ ln2_g,
                                              const float* __restrict__ ln2_b,
                                              float4* __restrict__ nodeAgg,
                                              float* __restrict__ consts) {
  if (blockIdx.x == 0) {
    __shared__ float r1[256], r2[256];
    int c = threadIdx.x;
    float vg = 0.f, vb = 0.f;
    if (c < 2 * HP + 1) {
      float aw = attn_w[c];
      vg = aw * ln2_g[c];
      vb = aw * ln2_b[c];
    }
    r1[c] = vg; r2[c] = vb;
    __syncthreads();
    for (int off = 128; off > 0; off >>= 1) {
      if (c < off) { r1[c] += r1[c + off]; r2[c] += r2[c + off]; }
      __syncthreads();
    }
    if (c == 0) {
      consts[0] = r1[0];                                // S_wg
      consts[1] = r2[0];                                // S_wb
      consts[2] = attn_w[2 * HP] * ln2_g[2 * HP];       // wg for the T column
      consts[3] = 0.f;
    }
  }

  int t = blockIdx.x * 256 + threadIdx.x;
  if (t >= NN * NB) return;
  v2 row2[6];
  load_row12v(feature + (size_t)t * TT, row2);
  const v2* wv  = reinterpret_cast<const v2*>(fc_w);    // [64][6]
  const v2* awv = reinterpret_cast<const v2*>(attn_w);
  const v2* gv  = reinterpret_cast<const v2*>(ln2_g);
  v2 A1p = {0.f,0.f}, A2p = {0.f,0.f}, Dsp = {0.f,0.f}, Ddp = {0.f,0.f};
#pragma unroll
  for (int c2 = 0; c2 < HP / 2; ++c2) {
    v2 a0 = {0.f,0.f}, a1 = {0.f,0.f};
#pragma unroll
    for (int k2 = 0; k2 < 6; ++k2) {
      a0 = fma2(row2[k2], wv[(2 * c2) * 6 + k2], a0);
      a1 = fma2(row2[k2], wv[(2 * c2 + 1) * 6 + k2], a1);
    }
    v2 zp = {a0.x + a0.y, a1.x + a1.y};
    A1p += zp;
    A2p = fma2(zp, zp, A2p);
    v2 wgs = awv[c2] * gv[c2];
    v2 wgd = awv[HP / 2 + c2] * gv[HP / 2 + c2];
    Dsp = fma2(wgs, zp, Dsp);
    Ddp = fma2(wgd, zp, Ddp);
  }
  float4 o;
  o.x = A1p.x + A1p.y; o.y = A2p.x + A2p.y; o.z = Dsp.x + Dsp.y; o.w = Ddp.x + Ddp.y;
  nodeAgg[t] = o;
}

// ---------------- per-(edge,batch): dual-NAM (interleaved ILP), diffusion, attention ----------------
__global__ __launch_bounds__(256) void k_edge1(
    const float* __restrict__ upstream, const float* __restrict__ downstream,
    const float* __restrict__ distance, const float* __restrict__ alpha,
    const int* __restrict__ src, const int* __restrict__ dst,
    const float* __restrict__ feature, const float4* __restrict__ nodeAgg,
    const float* __restrict__ l11_w, const float* __restrict__ l11_b,
    const float* __restrict__ ln11_g, const float* __restrict__ ln11_b,
    const float* __restrict__ l12_w, const float* __restrict__ l12_b,
    const float* __restrict__ l21_w, const float* __restrict__ l21_b,
    const float* __restrict__ ln21_g, const float* __restrict__ ln21_b,
    const float* __restrict__ l22_w, const float* __restrict__ l22_b,
    const float* __restrict__ l3_w, const float* __restrict__ l3_b,
    const float* __restrict__ consts,
    float* __restrict__ prod, float* __restrict__ den) {
  int t = blockIdx.x * 256 + threadIdx.x;
  int e = t >> 3, b = t & 7;

  // ---- issue ALL gathers up front; their latency hides under the NAM math ----
  int se = src[e], de = dst[e];
  float al = alpha[e];
  float dist = distance[e];
  const float4* fp4 = reinterpret_cast<const float4*>(feature + ((size_t)se * NB + b) * TT);
  float4 f0 = fp4[0], f1 = fp4[1], f2 = fp4[2];
  float4 As = nodeAgg[(size_t)se * NB + b];
  float4 Ad = nodeAgg[(size_t)de * NB + b];

  v2 ru[6], rd[6];
  load_row12v(upstream + (size_t)t * TT, ru);
  load_row12v(downstream + (size_t)t * TT, rd);

  // ---- dual-branch NAM matvec: 4 independent fma2 chains per j2 ----
  const v2* wu  = reinterpret_cast<const v2*>(l11_w);   // [32][6]
  const v2* wd  = reinterpret_cast<const v2*>(l21_w);
  const v2* buv = reinterpret_cast<const v2*>(l11_b);
  const v2* bdv = reinterpret_cast<const v2*>(l21_b);
  v2 hu[HV / 2], hd[HV / 2];
  v2 su1 = {0.f,0.f}, su2 = {0.f,0.f}, sn1 = {0.f,0.f}, sn2 = {0.f,0.f};
#pragma unroll
  for (int j2 = 0; j2 < HV / 2; ++j2) {
    v2 au0 = {0.f,0.f}, au1 = {0.f,0.f}, ad0 = {0.f,0.f}, ad1 = {0.f,0.f};
#pragma unroll
    for (int k2 = 0; k2 < 6; ++k2) {
      au0 = fma2(ru[k2], wu[(2 * j2) * 6 + k2], au0);
      au1 = fma2(ru[k2], wu[(2 * j2 + 1) * 6 + k2], au1);
      ad0 = fma2(rd[k2], wd[(2 * j2) * 6 + k2], ad0);
      ad1 = fma2(rd[k2], wd[(2 * j2 + 1) * 6 + k2], ad1);
    }
    v2 bu = buv[j2], bd = bdv[j2];
    v2 hhu = {au0.x + au0.y + bu.x, au1.x + au1.y + bu.y};
    v2 hhd = {ad0.x + ad0.y + bd.x, ad1.x + ad1.y + bd.y};
    hu[j2] = hhu; hd[j2] = hhd;
    su1 += hhu; su2 = fma2(hhu, hhu, su2);
    sn1 += hhd; sn2 = fma2(hhd, hhd, sn2);
  }
  // LN stats (per branch, same op order as R4's nam_branch)
  float s1u = su1.x + su1.y, s2u = su2.x + su2.y;
  float s1d = sn1.x + sn1.y, s2d = sn2.x + sn2.y;
  float mu_ = s1u * (1.f / HV);
  float varu = s2u * (1.f / HV) - mu_ * mu_;
  float invu = rsqrtf(varu + 1e-5f);
  float md_ = s1d * (1.f / HV);
  float vard = s2d * (1.f / HV) - md_ * md_;
  float invd = rsqrtf(vard + 1e-5f);
  v2 invu2 = {invu, invu}, invd2 = {invd, invd};
  float nmu = -mu_ * invu, nmd = -md_ * invd;
  v2 nmu2 = {nmu, nmu}, nmd2 = {nmd, nmd};

  const v2* guv  = reinterpret_cast<const v2*>(ln11_g);
  const v2* bbuv = reinterpret_cast<const v2*>(ln11_b);
  const v2* w2uv = reinterpret_cast<const v2*>(l12_w);
  const v2* gdv  = reinterpret_cast<const v2*>(ln21_g);
  const v2* bbdv = reinterpret_cast<const v2*>(ln21_b);
  const v2* w2dv = reinterpret_cast<const v2*>(l22_w);
  v2 accu = {0.f,0.f}, accd = {0.f,0.f};
  v2 zero = {0.f,0.f};
#pragma unroll
  for (int j2 = 0; j2 < HV / 2; ++j2) {
    v2 tu = fma2(hu[j2], invu2, nmu2);
    v2 yu = fma2(tu, guv[j2], bbuv[j2]);
    yu = __builtin_elementwise_max(yu, zero);
    accu = fma2(yu, w2uv[j2], accu);
    v2 td = fma2(hd[j2], invd2, nmd2);
    v2 yd = fma2(td, gdv[j2], bbdv[j2]);
    yd = __builtin_elementwise_max(yd, zero);
    accd = fma2(yd, w2dv[j2], accd);
  }
  float xu = 1.f / (1.f + __expf(-(accu.x + accu.y + l12_b[0])));
  float xd = 1.f / (1.f + __expf(-(accd.x + accd.y + l22_b[0])));

  float vp = fmaf(l3_w[0], xu, fmaf(l3_w[1], xd, fmaf(l3_w[2], al, l3_b[0])));
  float v = fmaxf(vp, 0.f) + log1pf(__expf(-fabsf(vp)));  // stable softplus
  v = fminf(v, 3.f);
  float Tt = dist / (v + 1e-5f);                           // IEEE div: rounding cliff below
  float Ti = fminf(fmaxf(rintf(Tt * 0.1f), 0.f), (float)(TT - 1));
  int n = TT - (int)Ti;  // 1..12
  float acl = fminf(fmaxf(al, 0.f), 1.f);
  float F = 1.f / (1.f + acl * Tt);
  float omF = 1.f - F;

  // diffusion-weighted feature[src] sum: F * sum_{k<n} (1-F)^(n-1-k) f[k]
  float row[TT];
  row[0]=f0.x; row[1]=f0.y; row[2]=f0.z; row[3]=f0.w;
  row[4]=f1.x; row[5]=f1.y; row[6]=f1.z; row[7]=f1.w;
  row[8]=f2.x; row[9]=f2.y; row[10]=f2.z; row[11]=f2.w;
  float pw = 1.f, s = 0.f;
#pragma unroll
  for (int k = TT - 1; k >= 0; --k) {
    if (k <= n - 1) { s = fmaf(pw, row[k], s); pw *= omF; }
  }
  s *= F;

  // attention logit from node aggregates (collapsed LN+dot)
  float s1 = As.x + Ad.x + Tt;
  float s2 = As.y + Ad.y + Tt * Tt;
  float sd = As.z + Ad.w + consts[2] * Tt;

  float m = s1 * (1.f / 129.f);
  float var = s2 * (1.f / 129.f) - m * m;
  float inv = rsqrtf(var + 1e-5f);
  float a = fmaf(inv, sd - m * consts[0], consts[1]);
  a = (a >= 0.f) ? a : 0.01f * a;  // leaky_relu 0.01

  // no segment-max needed: |a| bounded (Cauchy-Schwarz on normalized zc) -> no exp overflow
  float ex = __expf(a);
  prod[t] = ex * s;
  atomicAdd(&den[(size_t)se * NB + b], ex);
}

// ---------------- scatter: pred[dst] += prod / den[src] ----------------
__global__ __launch_bounds__(256) void k_edge2(const int* __restrict__ src,
                                               const int* __restrict__ dst,
                                               const float* __restrict__ prod,
                                               const float* __restrict__ den,
                                               float* __restrict__ pred) {
  int t = blockIdx.x * 256 + threadIdx.x;
  int e = t >> 3, b = t & 7;
  float p = prod[t] / den[(size_t)src[e] * NB + b];        // IEEE div
  atomicAdd(&pred[(size_t)dst[e] * NB + b], p);
}

extern "C" void kernel_launch(void* const* d_in, const int* in_sizes, int n_in,
                              void* d_out, int out_size, void* d_ws, size_t ws_size,
                              hipStream_t stream) {
  const float* feature   = (const float*)d_in[0];
  const float* upstream  = (const float*)d_in[1];
  const float* downstream= (const float*)d_in[2];
  const float* distance  = (const float*)d_in[3];
  const int*   src       = (const int*)d_in[4];
  const int*   dst       = (const int*)d_in[5];
  const float* alpha     = (const float*)d_in[6];
  const float* fc_w      = (const float*)d_in[7];
  const float* ln2_g     = (const float*)d_in[8];
  const float* ln2_b     = (const float*)d_in[9];
  const float* attn_w    = (const float*)d_in[10];
  const float* l11_w     = (const float*)d_in[11];
  const float* l11_b     = (const float*)d_in[12];
  const float* ln11_g    = (const float*)d_in[13];
  const float* ln11_b    = (const float*)d_in[14];
  const float* l12_w     = (const float*)d_in[15];
  const float* l12_b     = (const float*)d_in[16];
  const float* l21_w     = (const float*)d_in[17];
  const float* l21_b     = (const float*)d_in[18];
  const float* ln21_g    = (const float*)d_in[19];
  const float* ln21_b    = (const float*)d_in[20];
  const float* l22_w     = (const float*)d_in[21];
  const float* l22_b     = (const float*)d_in[22];
  const float* l3_w      = (const float*)d_in[23];
  const float* l3_b      = (const float*)d_in[24];
  float* pred = (float*)d_out;

  // ws layout (floats): nodeAgg[NN*NB*4] | prod[NE*NB] | den[NN*NB] | consts[4]
  float* ws = (float*)d_ws;
  float4* nodeAgg = (float4*)ws;
  float* prod   = ws + (size_t)NN * NB * 4;
  float* den    = prod + (size_t)NE * NB;
  float* consts = den + (size_t)NN * NB;

  k_init<<<(NN * NB / 4 + 255) / 256, 256, 0, stream>>>((float4*)den, (float4*)pred);
  k_node<<<(NN * NB + 255) / 256, 256, 0, stream>>>(feature, fc_w, attn_w, ln2_g, ln2_b,
                                                    nodeAgg, consts);

  int eb = NE * NB;
  k_edge1<<<eb / 256, 256, 0, stream>>>(upstream, downstream, distance, alpha, src, dst,
                                        feature, nodeAgg,
                                        l11_w, l11_b, ln11_g, ln11_b, l12_w, l12_b,
                                        l21_w, l21_b, ln21_g, ln21_b, l22_w, l22_b,
                                        l3_w, l3_b, consts, prod, den);
  k_edge2<<<eb / 256, 256, 0, stream>>>(src, dst, prod, den, pred);
}